// Round 5
// baseline (25633.154 us; speedup 1.0000x reference)
//
#include <hip/hip_runtime.h>

typedef unsigned short u16;
typedef unsigned int   u32;

__device__ __forceinline__ u16 f2bf(float f){
  u32 u = __float_as_uint(f);
  return (u16)((u + 0x7fffu + ((u >> 16) & 1u)) >> 16);  // RNE
}

// Decode grid_sizes robustly against int32-vs-int64 storage (kept from r4; proven harmless).
__device__ __forceinline__ void read_gsz(const int* g, int seqlen, int& F, int& H, int& W)
{
  int a0 = g[0], a1 = g[1], a2 = g[2];
  if (a0 > 0 && a1 > 0 && a2 > 0 && (long long)a0 * a1 * a2 == seqlen) { F = a0; H = a1; W = a2; return; }
  int b0 = g[0], b1 = g[2], b2 = g[4];         // int64 LE pattern: values at words 0,2,4
  if (b0 > 0 && b1 > 0 && b2 > 0 && (long long)b0 * b1 * b2 == seqlen) { F = b0; H = b1; W = b2; return; }
  if (a0 > 0 && a1 > 0 && a2 > 0 && (long long)a0 * a1 * a2 <= seqlen) { F = a0; H = a1; W = a2; return; }
  if (b0 > 0 && b1 > 0 && b2 > 0 && (long long)b0 * b1 * b2 <= seqlen) { F = b0; H = b1; W = b2; return; }
  F = a0; H = a1; W = a2;
}

// ---------------------------------------------------------------------------
// Plain fp32 vector GEMM. C[M][1536] = A[M][1536] @ W[1536][1536] + bias.
// 64x64 tile, 256 threads, 4x4 micro-tile per thread, K-step 16.
// ---------------------------------------------------------------------------
template<bool BF16_OUT>
__global__ __launch_bounds__(256) void vgemm(
    const float* __restrict__ A, const float* __restrict__ W,
    const float* __restrict__ bias, void* __restrict__ Cv, int M)
{
  __shared__ float As[16][68];   // [k][m], padded
  __shared__ float Ws[16][64];   // [k][n]
  const int tid = threadIdx.x;
  const int tm = tid >> 4, tn = tid & 15;
  const int m0 = blockIdx.x * 64, n0 = blockIdx.y * 64;
  float acc[4][4] = {};
  for (int k0 = 0; k0 < 1536; k0 += 16) {
    __syncthreads();
    {  // stage A tile: 64 rows x 16 k
      int r  = tid >> 2;            // 0..63
      int kk = (tid & 3) * 4;       // 0,4,8,12
      float4 a4 = {0.f, 0.f, 0.f, 0.f};
      int gr = m0 + r;
      if (gr < M) a4 = *(const float4*)(A + (size_t)gr * 1536 + k0 + kk);
      As[kk][r] = a4.x; As[kk + 1][r] = a4.y; As[kk + 2][r] = a4.z; As[kk + 3][r] = a4.w;
    }
    {  // stage W tile: 16 k x 64 n (coalesced, W row-major [K][N])
      int kk = tid >> 4;            // 0..15
      int n  = (tid & 15) * 4;      // 0..60
      *(float4*)&Ws[kk][n] = *(const float4*)(W + (size_t)(k0 + kk) * 1536 + n0 + n);
    }
    __syncthreads();
#pragma unroll
    for (int kk = 0; kk < 16; kk++) {
      float a[4], w[4];
#pragma unroll
      for (int i = 0; i < 4; i++) a[i] = As[kk][tm * 4 + i];
#pragma unroll
      for (int j = 0; j < 4; j++) w[j] = Ws[kk][tn * 4 + j];
#pragma unroll
      for (int i = 0; i < 4; i++)
#pragma unroll
        for (int j = 0; j < 4; j++) acc[i][j] = fmaf(a[i], w[j], acc[i][j]);
    }
  }
#pragma unroll
  for (int i = 0; i < 4; i++) {
    int row = m0 + tm * 4 + i;
    if (row < M) {
#pragma unroll
      for (int j = 0; j < 4; j++) {
        int col = n0 + tn * 4 + j;
        float val = acc[i][j] + bias[col];
        if (BF16_OUT) ((u16*)Cv)[(size_t)row * 1536 + col] = f2bf(val);
        else          ((float*)Cv)[(size_t)row * 1536 + col] = val;
      }
    }
  }
}

// ---------------------------------------------------------------------------
// In-place RMSNorm (over full 1536) + per-head RoPE, all fp32.
// d=128, c=64 split 22/21/21 (f/h/w); freqs fp32 [1024][64].
// ---------------------------------------------------------------------------
__global__ __launch_bounds__(256) void rmsrope(
    float* __restrict__ qb, float* __restrict__ kb,
    const float* __restrict__ gq, const float* __restrict__ gk,
    const float* __restrict__ freqs, const int* __restrict__ gsz,
    const int* __restrict__ seq_lens)
{
  const int s = blockIdx.x, tid = threadIdx.x;
  const size_t base = (size_t)s * 1536;
  float qv[6], kv[6];
  float sq = 0.f, sk = 0.f;
#pragma unroll
  for (int i = 0; i < 6; i++) {
    float a = qb[base + tid * 6 + i]; qv[i] = a; sq += a * a;
    float b = kb[base + tid * 6 + i]; kv[i] = b; sk += b * b;
  }
#pragma unroll
  for (int d2 = 1; d2 < 64; d2 <<= 1) { sq += __shfl_xor(sq, d2); sk += __shfl_xor(sk, d2); }
  __shared__ float red[8];
  const int wave = tid >> 6, lane = tid & 63;
  if (lane == 0) { red[wave] = sq; red[4 + wave] = sk; }
  __syncthreads();
  sq = red[0] + red[1] + red[2] + red[3];
  sk = red[4] + red[5] + red[6] + red[7];
  const float rq = rsqrtf(sq * (1.f / 1536.f) + 1e-6f);
  const float rk = rsqrtf(sk * (1.f / 1536.f) + 1e-6f);
  int F, H, W;
  read_gsz(gsz, seq_lens[0], F, H, W);
  const int sl = F * H * W;
  const bool rope = s < sl;
  int pf = 0, ph = 0, pw = 0;
  if (rope) { pf = s / (H * W); int rr = s - pf * (H * W); ph = rr / W; pw = rr - ph * W; }
#pragma unroll
  for (int pp = 0; pp < 3; pp++) {
    const int j0 = tid * 6 + pp * 2;
    float qre = qv[pp * 2]     * rq * gq[j0];
    float qim = qv[pp * 2 + 1] * rq * gq[j0 + 1];
    float kre = kv[pp * 2]     * rk * gk[j0];
    float kim = kv[pp * 2 + 1] * rk * gk[j0 + 1];
    if (rope) {
      const int ti = (j0 & 127) >> 1;                 // pair index within head, 0..63
      const int pos = ti < 22 ? pf : (ti < 43 ? ph : pw);
      const float ang = freqs[pos * 64 + ti];
      const float cs = cosf(ang), sn = sinf(ang);
      float t1 = qre * cs - qim * sn; qim = qre * sn + qim * cs; qre = t1;
      float t2 = kre * cs - kim * sn; kim = kre * sn + kim * cs; kre = t2;
    }
    qb[base + j0] = qre; qb[base + j0 + 1] = qim;
    kb[base + j0] = kre; kb[base + j0 + 1] = kim;
  }
}

// ---------------------------------------------------------------------------
// fp32 vector flash attention. Block = 4 waves, each wave owns one q row;
// 32-key K/V tiles in LDS; online softmax; lane owns dims {2*lane, 2*lane+1}.
// ---------------------------------------------------------------------------
__global__ __launch_bounds__(256) void attn_k(
    const float* __restrict__ q, const float* __restrict__ k, const float* __restrict__ v,
    float* __restrict__ o, const int* __restrict__ seq_lens, int L)
{
  __shared__ float Ks[32][128];
  __shared__ float Vs[32][128];
  __shared__ float Qs[4][128];
  __shared__ float Ps[4][32];
  const int tid = threadIdx.x, wave = tid >> 6, lane = tid & 63;
  const int h = blockIdx.y;
  const int q0 = blockIdx.x * 4;
  const int seqlen = seq_lens[0];
  for (int e = tid; e < 512; e += 256) {
    int r = e >> 7, c = e & 127;
    int qr = q0 + r;
    Qs[r][c] = (qr < L) ? q[(size_t)qr * 1536 + h * 128 + c] * 0.08838834764831845f : 0.f;
  }
  float m = -1e30f, l = 0.f, a0 = 0.f, a1 = 0.f;
  const int vd = lane * 2;
  const int nk = (seqlen + 31) >> 5;
  for (int t = 0; t < nk; t++) {
    const int kbase = t * 32;
    const int kcount = min(32, seqlen - kbase);
    __syncthreads();
    for (int s4 = tid; s4 < 1024; s4 += 256) {    // 32 rows x 32 float4s
      int row = s4 >> 5, c4 = (s4 & 31) * 4;
      int gr = kbase + row;
      float4 kv4 = {0.f, 0.f, 0.f, 0.f}, vv4 = {0.f, 0.f, 0.f, 0.f};
      if (gr < seqlen) {
        kv4 = *(const float4*)(k + (size_t)gr * 1536 + h * 128 + c4);
        vv4 = *(const float4*)(v + (size_t)gr * 1536 + h * 128 + c4);
      }
      *(float4*)&Ks[row][c4] = kv4;
      *(float4*)&Vs[row][c4] = vv4;
    }
    __syncthreads();
    float s = -1e30f;
    if (lane < kcount) {
      s = 0.f;
#pragma unroll
      for (int j = 0; j < 128; j += 4) {
        float4 k4 = *(const float4*)&Ks[lane][j];
        float4 q4 = *(const float4*)&Qs[wave][j];
        s += k4.x * q4.x + k4.y * q4.y + k4.z * q4.z + k4.w * q4.w;
      }
    }
    float tmax = s;
#pragma unroll
    for (int d2 = 1; d2 < 64; d2 <<= 1) tmax = fmaxf(tmax, __shfl_xor(tmax, d2));
    float mnew = fmaxf(m, tmax);
    float alpha = __expf(m - mnew);
    float p = (lane < kcount) ? __expf(s - mnew) : 0.f;
    float ps = p;
#pragma unroll
    for (int d2 = 1; d2 < 64; d2 <<= 1) ps += __shfl_xor(ps, d2);
    l = l * alpha + ps;
    a0 *= alpha; a1 *= alpha;
    if (lane < 32) Ps[wave][lane] = p;
    m = mnew;
    for (int key = 0; key < kcount; key++) {
      float pk = Ps[wave][key];
      a0 = fmaf(pk, Vs[key][vd],     a0);
      a1 = fmaf(pk, Vs[key][vd + 1], a1);
    }
  }
  int qr = q0 + wave;
  if (qr < L) {
    float inv = 1.f / l;
    float2 r2 = { a0 * inv, a1 * inv };
    *(float2*)(o + (size_t)qr * 1536 + h * 128 + vd) = r2;
  }
}

// ---------------------------------------------------------------------------
extern "C" void kernel_launch(void* const* d_in, const int* in_sizes, int n_in,
                              void* d_out, int out_size, void* d_ws, size_t ws_size,
                              hipStream_t stream) {
  const float* x      = (const float*)d_in[0];
  const int* seq_lens = (const int*)d_in[1];
  const int* gsz      = (const int*)d_in[2];
  const float* freqs  = (const float*)d_in[3];
  const float* Wq     = (const float*)d_in[4];
  const float* bq     = (const float*)d_in[5];
  const float* Wk     = (const float*)d_in[6];
  const float* bk     = (const float*)d_in[7];
  const float* Wv     = (const float*)d_in[8];
  const float* bv     = (const float*)d_in[9];
  const float* Wo     = (const float*)d_in[10];
  const float* bo     = (const float*)d_in[11];
  const float* gq     = (const float*)d_in[12];
  const float* gk     = (const float*)d_in[13];
  float* out = (float*)d_out;   // <<< ROUND-5 CHANGE: reference output dtype is fp32

  const int DIM = 1536;
  const int L = in_sizes[0] / DIM;          // 5000
  const size_t SZT = (size_t)L * DIM;       // 7,680,000 elems

  // workspace (fp32): qraw | kraw | vraw | attn  (4 x 30.72 MB = 122.9 MB)
  float* qraw = (float*)d_ws;
  float* kraw = qraw + SZT;
  float* vraw = kraw + SZT;
  float* attn = vraw + SZT;

  const dim3 ggrid((L + 63) / 64, DIM / 64);

  vgemm<false><<<ggrid, 256, 0, stream>>>(x, Wq, bq, qraw, L);
  vgemm<false><<<ggrid, 256, 0, stream>>>(x, Wk, bk, kraw, L);
  vgemm<false><<<ggrid, 256, 0, stream>>>(x, Wv, bv, vraw, L);
  rmsrope<<<dim3(L), 256, 0, stream>>>(qraw, kraw, gq, gk, freqs, gsz, seq_lens);
  attn_k<<<dim3((L + 3) / 4, 12), 256, 0, stream>>>(qraw, kraw, vraw, attn, seq_lens, L);
  vgemm<false><<<ggrid, 256, 0, stream>>>(attn, Wo, bo, out, L);   // fp32 output
}

// Round 6
// 845.123 us; speedup vs baseline: 30.3307x; 30.3307x over previous
//
#include <hip/hip_runtime.h>

typedef unsigned short u16;
typedef unsigned int   u32;
typedef short bf16x8 __attribute__((ext_vector_type(8)));
typedef short bf16x4 __attribute__((ext_vector_type(4)));
typedef float f32x4  __attribute__((ext_vector_type(4)));

__device__ __forceinline__ float b2f(u16 u){ return __uint_as_float(((u32)u) << 16); }
__device__ __forceinline__ u16 f2bf(float f){
  u32 u = __float_as_uint(f);
  return (u16)((u + 0x7fffu + ((u >> 16) & 1u)) >> 16);  // RNE
}

// ---------------------------------------------------------------------------
// Transpose+cast four fp32 1536x1536 weights into bf16 WT[n][k]=W[k][n].
// ---------------------------------------------------------------------------
__global__ __launch_bounds__(256) void transpose4(
    const float* __restrict__ Wq, const float* __restrict__ Wk,
    const float* __restrict__ Wv, const float* __restrict__ Wo, u16* __restrict__ wt)
{
  __shared__ float tile[32][33];
  const float* src = blockIdx.z == 0 ? Wq : blockIdx.z == 1 ? Wk : blockIdx.z == 2 ? Wv : Wo;
  u16* dst = wt + (size_t)blockIdx.z * 1536 * 1536;
  const int bx = blockIdx.x * 32, by = blockIdx.y * 32;
  const int tx = threadIdx.x, ty = threadIdx.y;  // 32 x 8
#pragma unroll
  for (int i = 0; i < 32; i += 8)
    tile[ty + i][tx] = src[(size_t)(by + ty + i) * 1536 + bx + tx];
  __syncthreads();
#pragma unroll
  for (int i = 0; i < 32; i += 8)
    dst[(size_t)(bx + ty + i) * 1536 + by + tx] = f2bf(tile[tx][ty + i]);
}

// fp32 -> bf16 cast for x.
__global__ __launch_bounds__(256) void cast_f32_bf16(
    const float* __restrict__ src, u16* __restrict__ dst, int n4)
{
  int i = blockIdx.x * 256 + threadIdx.x;
  if (i < n4) {
    float4 f = ((const float4*)src)[i];
    ushort4 o;
    o.x = f2bf(f.x); o.y = f2bf(f.y); o.z = f2bf(f.z); o.w = f2bf(f.w);
    ((ushort4*)dst)[i] = o;
  }
}

// ---------------------------------------------------------------------------
// C[M][1536] = A[M][1536] @ BT^T + bias. bf16 MFMA, fp32 acc.
// 128x128 tile, 4 waves 2x2, 4x4 mfma 16x16x32 each.
// A-frag m=lane&15,k=(lane>>4)*8+j ; C/D row=(lane>>4)*4+r, col=lane&15  [m89/m91].
// ---------------------------------------------------------------------------
template<bool F32OUT>
__global__ __launch_bounds__(256) void gemm_bt(
    const u16* __restrict__ A, const u16* __restrict__ BT,
    const float* __restrict__ bias, void* __restrict__ Cv, int M)
{
  __shared__ u16 As[128][40];
  __shared__ u16 Bs[128][40];
  const int tid = threadIdx.x;
  const int wave = tid >> 6, lane = tid & 63;
  const int wm = (wave & 1) * 64, wn = (wave >> 1) * 64;
  const int l16 = lane & 15, quad = lane >> 4;
  const int m0 = blockIdx.x * 128, n0 = blockIdx.y * 128;
  f32x4 acc[4][4] = {};
  for (int k0 = 0; k0 < 1536; k0 += 32) {
    __syncthreads();
#pragma unroll
    for (int i = 0; i < 2; i++) {
      int c = tid + i * 256;
      int row = c >> 2, col = (c & 3) * 8;
      bf16x8 av = {0, 0, 0, 0, 0, 0, 0, 0};
      int gr = m0 + row;
      if (gr < M) av = *(const bf16x8*)(A + (size_t)gr * 1536 + k0 + col);
      *(bf16x8*)&As[row][col] = av;
      *(bf16x8*)&Bs[row][col] = *(const bf16x8*)(BT + (size_t)(n0 + row) * 1536 + k0 + col);
    }
    __syncthreads();
    bf16x8 af[4], bfr[4];
#pragma unroll
    for (int mt = 0; mt < 4; mt++) af[mt] = *(const bf16x8*)&As[wm + mt * 16 + l16][quad * 8];
#pragma unroll
    for (int nt = 0; nt < 4; nt++) bfr[nt] = *(const bf16x8*)&Bs[wn + nt * 16 + l16][quad * 8];
#pragma unroll
    for (int mt = 0; mt < 4; mt++)
#pragma unroll
      for (int nt = 0; nt < 4; nt++)
        acc[mt][nt] = __builtin_amdgcn_mfma_f32_16x16x32_bf16(af[mt], bfr[nt], acc[mt][nt], 0, 0, 0);
  }
#pragma unroll
  for (int nt = 0; nt < 4; nt++) {
    int col = n0 + wn + nt * 16 + l16;
    float bv = bias[col];
#pragma unroll
    for (int mt = 0; mt < 4; mt++) {
      int rowb = m0 + wm + mt * 16 + quad * 4;
#pragma unroll
      for (int r = 0; r < 4; r++) {
        int row = rowb + r;
        if (row < M) {
          float val = acc[mt][nt][r] + bv;
          if (F32OUT) ((float*)Cv)[(size_t)row * 1536 + col] = val;
          else        ((u16*)Cv)[(size_t)row * 1536 + col] = f2bf(val);
        }
      }
    }
  }
}

// ---------------------------------------------------------------------------
// In-place RMSNorm (dim 1536) + per-head RoPE on bf16 q/k; fp32 gains/freqs.
// d=128, c=64 split 22/21/21. gsz/seq_lens proven int32 (round 5).
// ---------------------------------------------------------------------------
__global__ __launch_bounds__(256) void rmsrope(
    u16* __restrict__ qb, u16* __restrict__ kb,
    const float* __restrict__ gq, const float* __restrict__ gk,
    const float* __restrict__ freqs, const int* __restrict__ gsz)
{
  const int s = blockIdx.x, tid = threadIdx.x;
  const size_t base = (size_t)s * 1536;
  float qv[6], kv[6];
  float sq = 0.f, sk = 0.f;
#pragma unroll
  for (int i = 0; i < 6; i++) {
    float a = b2f(qb[base + tid * 6 + i]); qv[i] = a; sq += a * a;
    float b = b2f(kb[base + tid * 6 + i]); kv[i] = b; sk += b * b;
  }
#pragma unroll
  for (int d2 = 1; d2 < 64; d2 <<= 1) { sq += __shfl_xor(sq, d2); sk += __shfl_xor(sk, d2); }
  __shared__ float red[8];
  const int wave = tid >> 6, lane = tid & 63;
  if (lane == 0) { red[wave] = sq; red[4 + wave] = sk; }
  __syncthreads();
  sq = red[0] + red[1] + red[2] + red[3];
  sk = red[4] + red[5] + red[6] + red[7];
  const float rq = rsqrtf(sq * (1.f / 1536.f) + 1e-6f);
  const float rk = rsqrtf(sk * (1.f / 1536.f) + 1e-6f);
  const int F = gsz[0], H = gsz[1], W = gsz[2]; (void)F;
  const int sl = F * H * W;
  const bool rope = s < sl;
  int pf = 0, ph = 0, pw = 0;
  if (rope) { pf = s / (H * W); int rr = s - pf * (H * W); ph = rr / W; pw = rr - ph * W; }
#pragma unroll
  for (int pp = 0; pp < 3; pp++) {
    const int j0 = tid * 6 + pp * 2;
    float qre = qv[pp * 2]     * rq * gq[j0];
    float qim = qv[pp * 2 + 1] * rq * gq[j0 + 1];
    float kre = kv[pp * 2]     * rk * gk[j0];
    float kim = kv[pp * 2 + 1] * rk * gk[j0 + 1];
    if (rope) {
      const int ti = (j0 & 127) >> 1;
      const int pos = ti < 22 ? pf : (ti < 43 ? ph : pw);
      const float ang = freqs[pos * 64 + ti];
      const float cs = cosf(ang), sn = sinf(ang);
      float t1 = qre * cs - qim * sn; qim = qre * sn + qim * cs; qre = t1;
      float t2 = kre * cs - kim * sn; kim = kre * sn + kim * cs; kre = t2;
    }
    qb[base + j0] = f2bf(qre); qb[base + j0 + 1] = f2bf(qim);
    kb[base + j0] = f2bf(kre); kb[base + j0 + 1] = f2bf(kim);
  }
}

// ---------------------------------------------------------------------------
// MFMA flash attention. Block = 4 waves = 64 q rows (16/wave), one head.
// S^T via A=K,B=Q (both contiguous-d); column softmax (2 shfl_xor);
// P^T -> per-wave LDS -> A-frag; V staged transposed [d][key] in LDS;
// O in C-layout fp32, online-softmax rescale via lane shuffles.
// ---------------------------------------------------------------------------
__global__ __launch_bounds__(256) void attn_mfma(
    const u16* __restrict__ q, const u16* __restrict__ k, const u16* __restrict__ v,
    u16* __restrict__ o, const int* __restrict__ seq_lens, int L)
{
  __shared__ u16 Ks[32][136];     // K rows [key][d], pad 8
  __shared__ u16 Vt[128][40];     // V^T [d][key], pad 8
  __shared__ u16 Pl[4][16][40];   // per-wave P [q][key], pad 8
  const int tid = threadIdx.x, wave = tid >> 6, lane = tid & 63;
  const int l16 = lane & 15, quad = lane >> 4;
  const int h = blockIdx.y;
  const int seqlen = seq_lens[0];
  const int q0 = blockIdx.x * 64 + wave * 16;
  const float scale = 0.08838834764831845f;

  // Q fragments (loop-invariant, registers): B[n=q=l16][kk=quad*8+j], d=dstep*32+kk
  bf16x8 Qf[4];
  {
    int qr = q0 + l16;
#pragma unroll
    for (int dstep = 0; dstep < 4; dstep++) {
      bf16x8 z = {0, 0, 0, 0, 0, 0, 0, 0};
      if (qr < L) z = *(const bf16x8*)(q + (size_t)qr * 1536 + h * 128 + dstep * 32 + quad * 8);
      Qf[dstep] = z;
    }
  }
  f32x4 accO[8];
#pragma unroll
  for (int dt = 0; dt < 8; dt++) accO[dt] = (f32x4){0.f, 0.f, 0.f, 0.f};
  float m_i = -1e30f, l_i = 0.f;

  const int ntile = (seqlen + 31) >> 5;
  for (int t = 0; t < ntile; t++) {
    const int kb = t * 32;
    __syncthreads();
    // stage K rows: 32x128 = 512 octets
#pragma unroll
    for (int i = 0; i < 2; i++) {
      int slot = tid + i * 256;
      int row = slot >> 4, oct = slot & 15;
      bf16x8 z = {0, 0, 0, 0, 0, 0, 0, 0};
      if (kb + row < seqlen) z = *(const bf16x8*)(k + (size_t)(kb + row) * 1536 + h * 128 + oct * 8);
      *(bf16x8*)&Ks[row][oct * 8] = z;
    }
    // stage V transposed: thread = (d = tid&127, key-octet); coalesced 2B column loads
    {
      int d = tid & 127, ko2 = tid >> 7;  // 0..1
#pragma unroll
      for (int pass = 0; pass < 2; pass++) {
        int oct = pass * 2 + ko2;
        bf16x8 vv;
#pragma unroll
        for (int j = 0; j < 8; j++) {
          int key = kb + oct * 8 + j;
          u16 val = (key < seqlen) ? v[(size_t)key * 1536 + h * 128 + d] : (u16)0;
          vv[j] = (short)val;
        }
        *(bf16x8*)&Vt[d][oct * 8] = vv;
      }
    }
    __syncthreads();

    // S^T: two 16(key)x16(q) tiles, kdim = d
    f32x4 st[2];
#pragma unroll
    for (int kt = 0; kt < 2; kt++) {
      f32x4 a = {0.f, 0.f, 0.f, 0.f};
#pragma unroll
      for (int dstep = 0; dstep < 4; dstep++) {
        bf16x8 kf = *(const bf16x8*)&Ks[kt * 16 + l16][dstep * 32 + quad * 8];
        a = __builtin_amdgcn_mfma_f32_16x16x32_bf16(kf, Qf[dstep], a, 0, 0, 0);
      }
      st[kt] = a;
    }
    // column softmax (column = q = l16); lane holds keys {kt*16+quad*4+r}
    float sv[8];
    float tmax = -1e30f;
#pragma unroll
    for (int kt = 0; kt < 2; kt++)
#pragma unroll
      for (int r = 0; r < 4; r++) {
        int key = kb + kt * 16 + quad * 4 + r;
        float s = (key < seqlen) ? st[kt][r] * scale : -1e30f;
        sv[kt * 4 + r] = s;
        tmax = fmaxf(tmax, s);
      }
    tmax = fmaxf(tmax, __shfl_xor(tmax, 16));
    tmax = fmaxf(tmax, __shfl_xor(tmax, 32));
    float mnew = fmaxf(m_i, tmax);
    float alpha = __expf(m_i - mnew);
    float psum = 0.f;
    bf16x4 p0, p1;
#pragma unroll
    for (int i2 = 0; i2 < 8; i2++) {
      float p = (sv[i2] > -1e29f) ? __expf(sv[i2] - mnew) : 0.f;
      psum += p;
      if (i2 < 4) p0[i2] = (short)f2bf(p); else p1[i2 - 4] = (short)f2bf(p);
    }
    psum += __shfl_xor(psum, 16);
    psum += __shfl_xor(psum, 32);
    l_i = l_i * alpha + psum;
    m_i = mnew;
    // write P^T -> Pl[wave][q=l16][key] (8B stores)
    *(bf16x4*)&Pl[wave][l16][quad * 4]      = p0;
    *(bf16x4*)&Pl[wave][l16][16 + quad * 4] = p1;
    // rescale accO rows (row q-index = quad*4+r; stats live at lane l16==that index)
    float ar[4];
#pragma unroll
    for (int r = 0; r < 4; r++) ar[r] = __shfl(alpha, quad * 4 + r);
#pragma unroll
    for (int dt = 0; dt < 8; dt++)
#pragma unroll
      for (int r = 0; r < 4; r++) accO[dt][r] *= ar[r];
    // PV: A=P[q][key], B=Vt[d][key]; one mfma per 16-d tile covers all 32 keys
    bf16x8 pf = *(const bf16x8*)&Pl[wave][l16][quad * 8];
#pragma unroll
    for (int dt = 0; dt < 8; dt++) {
      bf16x8 vf = *(const bf16x8*)&Vt[dt * 16 + l16][quad * 8];
      accO[dt] = __builtin_amdgcn_mfma_f32_16x16x32_bf16(pf, vf, accO[dt], 0, 0, 0);
    }
  }
  // epilogue: O[q=quad*4+r][d=dt*16+l16] / l
  float linv[4];
#pragma unroll
  for (int r = 0; r < 4; r++) { float lr = __shfl(l_i, quad * 4 + r); linv[r] = 1.f / lr; }
#pragma unroll
  for (int r = 0; r < 4; r++) {
    int qr = q0 + quad * 4 + r;
    if (qr < L) {
#pragma unroll
      for (int dt = 0; dt < 8; dt++)
        o[(size_t)qr * 1536 + h * 128 + dt * 16 + l16] = f2bf(accO[dt][r] * linv[r]);
    }
  }
}

// ---------------------------------------------------------------------------
extern "C" void kernel_launch(void* const* d_in, const int* in_sizes, int n_in,
                              void* d_out, int out_size, void* d_ws, size_t ws_size,
                              hipStream_t stream) {
  const float* x      = (const float*)d_in[0];
  const int* seq_lens = (const int*)d_in[1];
  const int* gsz      = (const int*)d_in[2];
  const float* freqs  = (const float*)d_in[3];
  const float* Wq     = (const float*)d_in[4];
  const float* bq     = (const float*)d_in[5];
  const float* Wk     = (const float*)d_in[6];
  const float* bk     = (const float*)d_in[7];
  const float* Wv     = (const float*)d_in[8];
  const float* bv     = (const float*)d_in[9];
  const float* Wo     = (const float*)d_in[10];
  const float* bo     = (const float*)d_in[11];
  const float* gq     = (const float*)d_in[12];
  const float* gk     = (const float*)d_in[13];
  float* out = (float*)d_out;   // reference output dtype: fp32 (proven round 5)

  const int DIM = 1536;
  const int L = in_sizes[0] / DIM;          // 5000
  const size_t SZW = (size_t)DIM * DIM;
  const size_t SZT = (size_t)L * DIM;

  // workspace (bf16): WT[4] | xb | qraw | kraw | vraw | attn  (~95.7 MB)
  u16* wt   = (u16*)d_ws;
  u16* xb   = wt + 4 * SZW;
  u16* qraw = xb + SZT;
  u16* kraw = qraw + SZT;
  u16* vraw = kraw + SZT;
  u16* attn = vraw + SZT;

  const int mtiles = (L + 127) / 128;

  transpose4<<<dim3(48, 48, 4), dim3(32, 8), 0, stream>>>(Wq, Wk, Wv, Wo, wt);
  cast_f32_bf16<<<(int)((SZT / 4 + 255) / 256), 256, 0, stream>>>(x, xb, (int)(SZT / 4));
  gemm_bt<false><<<dim3(mtiles, 12), 256, 0, stream>>>(xb, wt,           bq, qraw, L);
  gemm_bt<false><<<dim3(mtiles, 12), 256, 0, stream>>>(xb, wt + SZW,     bk, kraw, L);
  gemm_bt<false><<<dim3(mtiles, 12), 256, 0, stream>>>(xb, wt + 2 * SZW, bv, vraw, L);
  rmsrope<<<dim3(L), 256, 0, stream>>>(qraw, kraw, gq, gk, freqs, gsz);
  attn_mfma<<<dim3((L + 63) / 64, 12), 256, 0, stream>>>(qraw, kraw, vraw, attn, seq_lens, L);
  gemm_bt<true><<<dim3(mtiles, 12), 256, 0, stream>>>(attn, wt + 3 * SZW, bo, out, L);
}

// Round 7
// 825.653 us; speedup vs baseline: 31.0459x; 1.0236x over previous
//
#include <hip/hip_runtime.h>

typedef unsigned short u16;
typedef unsigned int   u32;
typedef short bf16x8 __attribute__((ext_vector_type(8)));
typedef float f32x4  __attribute__((ext_vector_type(4)));

__device__ __forceinline__ float b2f(u16 u){ return __uint_as_float(((u32)u) << 16); }
__device__ __forceinline__ u16 f2bf(float f){
  u32 u = __float_as_uint(f);
  return (u16)((u + 0x7fffu + ((u >> 16) & 1u)) >> 16);  // RNE
}

// ---------------------------------------------------------------------------
// Transpose+cast four fp32 1536x1536 weights into bf16 WT[n][k]=W[k][n].
// ---------------------------------------------------------------------------
__global__ __launch_bounds__(256) void transpose4(
    const float* __restrict__ Wq, const float* __restrict__ Wk,
    const float* __restrict__ Wv, const float* __restrict__ Wo, u16* __restrict__ wt)
{
  __shared__ float tile[32][33];
  const float* src = blockIdx.z == 0 ? Wq : blockIdx.z == 1 ? Wk : blockIdx.z == 2 ? Wv : Wo;
  u16* dst = wt + (size_t)blockIdx.z * 1536 * 1536;
  const int bx = blockIdx.x * 32, by = blockIdx.y * 32;
  const int tx = threadIdx.x, ty = threadIdx.y;  // 32 x 8
#pragma unroll
  for (int i = 0; i < 32; i += 8)
    tile[ty + i][tx] = src[(size_t)(by + ty + i) * 1536 + bx + tx];
  __syncthreads();
#pragma unroll
  for (int i = 0; i < 32; i += 8)
    dst[(size_t)(bx + ty + i) * 1536 + by + tx] = f2bf(tile[tx][ty + i]);
}

// fp32 -> bf16 cast for x.
__global__ __launch_bounds__(256) void cast_f32_bf16(
    const float* __restrict__ src, u16* __restrict__ dst, int n4)
{
  int i = blockIdx.x * 256 + threadIdx.x;
  if (i < n4) {
    float4 f = ((const float4*)src)[i];
    ushort4 o;
    o.x = f2bf(f.x); o.y = f2bf(f.y); o.z = f2bf(f.z); o.w = f2bf(f.w);
    ((ushort4*)dst)[i] = o;
  }
}

// ---------------------------------------------------------------------------
// bf16 transpose: src[L][1536] -> dst[1536][Lpad], zero-padded keys >= L.
// 64x64 tiles; coalesced 16B on both sides (scalar LDS gather in between).
// ---------------------------------------------------------------------------
__global__ __launch_bounds__(256) void transpose_v(
    const u16* __restrict__ src, u16* __restrict__ dst, int L, int Lpad)
{
  __shared__ u16 tile[64][72];
  const int kb = blockIdx.x * 64, c0 = blockIdx.y * 64;
  const int tid = threadIdx.x;
#pragma unroll
  for (int i = 0; i < 2; i++) {
    int slot = tid + i * 256;
    int row = slot >> 3, oct = slot & 7;
    bf16x8 z = {0, 0, 0, 0, 0, 0, 0, 0};
    int key = kb + row;
    if (key < L) z = *(const bf16x8*)(src + (size_t)key * 1536 + c0 + oct * 8);
    *(bf16x8*)&tile[row][oct * 8] = z;
  }
  __syncthreads();
#pragma unroll
  for (int i = 0; i < 2; i++) {
    int slot = tid + i * 256;
    int d = slot >> 3, oct = slot & 7;
    bf16x8 z;
#pragma unroll
    for (int j = 0; j < 8; j++) z[j] = (short)tile[oct * 8 + j][d];
    *(bf16x8*)(dst + (size_t)(c0 + d) * Lpad + kb + oct * 8) = z;
  }
}

// ---------------------------------------------------------------------------
// C[M][1536] = A[M][1536] @ BT^T + bias. bf16 MFMA, fp32 acc.
// 128x128 tile, 4 waves 2x2, 4x4 mfma 16x16x32 each.  [verified r6]
// ---------------------------------------------------------------------------
template<bool F32OUT>
__global__ __launch_bounds__(256) void gemm_bt(
    const u16* __restrict__ A, const u16* __restrict__ BT,
    const float* __restrict__ bias, void* __restrict__ Cv, int M)
{
  __shared__ u16 As[128][40];
  __shared__ u16 Bs[128][40];
  const int tid = threadIdx.x;
  const int wave = tid >> 6, lane = tid & 63;
  const int wm = (wave & 1) * 64, wn = (wave >> 1) * 64;
  const int l16 = lane & 15, quad = lane >> 4;
  const int m0 = blockIdx.x * 128, n0 = blockIdx.y * 128;
  f32x4 acc[4][4] = {};
  for (int k0 = 0; k0 < 1536; k0 += 32) {
    __syncthreads();
#pragma unroll
    for (int i = 0; i < 2; i++) {
      int c = tid + i * 256;
      int row = c >> 2, col = (c & 3) * 8;
      bf16x8 av = {0, 0, 0, 0, 0, 0, 0, 0};
      int gr = m0 + row;
      if (gr < M) av = *(const bf16x8*)(A + (size_t)gr * 1536 + k0 + col);
      *(bf16x8*)&As[row][col] = av;
      *(bf16x8*)&Bs[row][col] = *(const bf16x8*)(BT + (size_t)(n0 + row) * 1536 + k0 + col);
    }
    __syncthreads();
    bf16x8 af[4], bfr[4];
#pragma unroll
    for (int mt = 0; mt < 4; mt++) af[mt] = *(const bf16x8*)&As[wm + mt * 16 + l16][quad * 8];
#pragma unroll
    for (int nt = 0; nt < 4; nt++) bfr[nt] = *(const bf16x8*)&Bs[wn + nt * 16 + l16][quad * 8];
#pragma unroll
    for (int mt = 0; mt < 4; mt++)
#pragma unroll
      for (int nt = 0; nt < 4; nt++)
        acc[mt][nt] = __builtin_amdgcn_mfma_f32_16x16x32_bf16(af[mt], bfr[nt], acc[mt][nt], 0, 0, 0);
  }
#pragma unroll
  for (int nt = 0; nt < 4; nt++) {
    int col = n0 + wn + nt * 16 + l16;
    float bv = bias[col];
#pragma unroll
    for (int mt = 0; mt < 4; mt++) {
      int rowb = m0 + wm + mt * 16 + quad * 4;
#pragma unroll
      for (int r = 0; r < 4; r++) {
        int row = rowb + r;
        if (row < M) {
          float val = acc[mt][nt][r] + bv;
          if (F32OUT) ((float*)Cv)[(size_t)row * 1536 + col] = val;
          else        ((u16*)Cv)[(size_t)row * 1536 + col] = f2bf(val);
        }
      }
    }
  }
}

// ---------------------------------------------------------------------------
// In-place RMSNorm (dim 1536) + per-head RoPE on bf16 q/k; fp32 gains/freqs.
// ---------------------------------------------------------------------------
__global__ __launch_bounds__(256) void rmsrope(
    u16* __restrict__ qb, u16* __restrict__ kb,
    const float* __restrict__ gq, const float* __restrict__ gk,
    const float* __restrict__ freqs, const int* __restrict__ gsz)
{
  const int s = blockIdx.x, tid = threadIdx.x;
  const size_t base = (size_t)s * 1536;
  float qv[6], kv[6];
  float sq = 0.f, sk = 0.f;
#pragma unroll
  for (int i = 0; i < 6; i++) {
    float a = b2f(qb[base + tid * 6 + i]); qv[i] = a; sq += a * a;
    float b = b2f(kb[base + tid * 6 + i]); kv[i] = b; sk += b * b;
  }
#pragma unroll
  for (int d2 = 1; d2 < 64; d2 <<= 1) { sq += __shfl_xor(sq, d2); sk += __shfl_xor(sk, d2); }
  __shared__ float red[8];
  const int wave = tid >> 6, lane = tid & 63;
  if (lane == 0) { red[wave] = sq; red[4 + wave] = sk; }
  __syncthreads();
  sq = red[0] + red[1] + red[2] + red[3];
  sk = red[4] + red[5] + red[6] + red[7];
  const float rq = rsqrtf(sq * (1.f / 1536.f) + 1e-6f);
  const float rk = rsqrtf(sk * (1.f / 1536.f) + 1e-6f);
  const int F = gsz[0], H = gsz[1], W = gsz[2];
  const int sl = F * H * W;
  const bool rope = s < sl;
  int pf = 0, ph = 0, pw = 0;
  if (rope) { pf = s / (H * W); int rr = s - pf * (H * W); ph = rr / W; pw = rr - ph * W; }
#pragma unroll
  for (int pp = 0; pp < 3; pp++) {
    const int j0 = tid * 6 + pp * 2;
    float qre = qv[pp * 2]     * rq * gq[j0];
    float qim = qv[pp * 2 + 1] * rq * gq[j0 + 1];
    float kre = kv[pp * 2]     * rk * gk[j0];
    float kim = kv[pp * 2 + 1] * rk * gk[j0 + 1];
    if (rope) {
      const int ti = (j0 & 127) >> 1;
      const int pos = ti < 22 ? pf : (ti < 43 ? ph : pw);
      const float ang = freqs[pos * 64 + ti];
      const float cs = cosf(ang), sn = sinf(ang);
      float t1 = qre * cs - qim * sn; qim = qre * sn + qim * cs; qre = t1;
      float t2 = kre * cs - kim * sn; kim = kre * sn + kim * cs; kre = t2;
    }
    qb[base + j0] = f2bf(qre); qb[base + j0 + 1] = f2bf(qim);
    kb[base + j0] = f2bf(kre); kb[base + j0 + 1] = f2bf(kim);
  }
}

// ---------------------------------------------------------------------------
// MFMA flash attention, 64-key tiles, pre-transposed V.
// Block = 4 waves = 64 q rows (16/wave), one head.
// S^T via A=K,B=Q; column softmax in log2 domain; P truncation-packed;
// V^T staged with coalesced 16B loads from vt[1536][Lpad].
// ---------------------------------------------------------------------------
__global__ __launch_bounds__(256) void attn_mfma(
    const u16* __restrict__ q, const u16* __restrict__ k, const u16* __restrict__ vt,
    u16* __restrict__ o, const int* __restrict__ seq_lens, int L, int Lpad)
{
  __shared__ u16 Ks[64][136];    // K rows [key][d], pad 8
  __shared__ u16 Vs[128][72];    // V^T [d][key], pad 8
  __shared__ u16 Pl[4][16][72];  // per-wave P [q][key], pad 8
  const int tid = threadIdx.x, wave = tid >> 6, lane = tid & 63;
  const int l16 = lane & 15, quad = lane >> 4;
  const int h = blockIdx.y;
  const int seqlen = seq_lens[0];
  const int q0 = blockIdx.x * 64 + wave * 16;
  const float SC = 0.12752551286084934f;   // (1/sqrt(128)) * log2(e)

  bf16x8 Qf[4];
  {
    int qr = q0 + l16;
#pragma unroll
    for (int ds = 0; ds < 4; ds++) {
      bf16x8 z = {0, 0, 0, 0, 0, 0, 0, 0};
      if (qr < L) z = *(const bf16x8*)(q + (size_t)qr * 1536 + h * 128 + ds * 32 + quad * 8);
      Qf[ds] = z;
    }
  }
  f32x4 accO[8];
#pragma unroll
  for (int dt = 0; dt < 8; dt++) accO[dt] = (f32x4){0.f, 0.f, 0.f, 0.f};
  float m_i = -1e30f, l_i = 0.f;

  const int ntile = (seqlen + 63) >> 6;
  for (int t = 0; t < ntile; t++) {
    const int kb = t * 64;
    __syncthreads();
    // stage K rows: 64x128 = 1024 octets, 4 per thread
#pragma unroll
    for (int i = 0; i < 4; i++) {
      int slot = tid + i * 256;
      int row = slot >> 4, oct = slot & 15;
      bf16x8 z = {0, 0, 0, 0, 0, 0, 0, 0};
      if (kb + row < seqlen) z = *(const bf16x8*)(k + (size_t)(kb + row) * 1536 + h * 128 + oct * 8);
      *(bf16x8*)&Ks[row][oct * 8] = z;
    }
    // stage V^T: 128 d x 64 keys = 1024 octets, 4 per thread (coalesced rows of vt)
#pragma unroll
    for (int i = 0; i < 4; i++) {
      int slot = tid + i * 256;
      int d = slot >> 3, oct = slot & 7;
      *(bf16x8*)&Vs[d][oct * 8] =
          *(const bf16x8*)(vt + (size_t)(h * 128 + d) * Lpad + kb + oct * 8);
    }
    __syncthreads();

    // S^T: four 16(key)x16(q) tiles over d=128
    float sv[16];
    float tmax = -1e30f;
#pragma unroll
    for (int kt = 0; kt < 4; kt++) {
      f32x4 a = {0.f, 0.f, 0.f, 0.f};
#pragma unroll
      for (int ds = 0; ds < 4; ds++) {
        bf16x8 kf = *(const bf16x8*)&Ks[kt * 16 + l16][ds * 32 + quad * 8];
        a = __builtin_amdgcn_mfma_f32_16x16x32_bf16(kf, Qf[ds], a, 0, 0, 0);
      }
#pragma unroll
      for (int r = 0; r < 4; r++) {
        int key = kb + kt * 16 + quad * 4 + r;
        float s = (key < seqlen) ? a[r] * SC : -1e30f;
        sv[kt * 4 + r] = s;
        tmax = fmaxf(tmax, s);
      }
    }
    tmax = fmaxf(tmax, __shfl_xor(tmax, 16));
    tmax = fmaxf(tmax, __shfl_xor(tmax, 32));
    const float mnew = fmaxf(m_i, tmax);
    const float alpha = exp2f(m_i - mnew);
    float psum = 0.f;
    u16 pk[16];
#pragma unroll
    for (int i2 = 0; i2 < 16; i2++) {
      float p = exp2f(sv[i2] - mnew);
      u32 pu = __float_as_uint(p) & 0xffff0000u;   // truncate to bf16
      psum += __uint_as_float(pu);                 // sum what PV will use
      pk[i2] = (u16)(pu >> 16);
    }
    psum += __shfl_xor(psum, 16);
    psum += __shfl_xor(psum, 32);
    l_i = l_i * alpha + psum;
    m_i = mnew;
    // write P^T -> Pl[wave][q=l16][key] (8B stores)
#pragma unroll
    for (int kt = 0; kt < 4; kt++) {
      ushort4 w4 = { pk[kt * 4], pk[kt * 4 + 1], pk[kt * 4 + 2], pk[kt * 4 + 3] };
      *(ushort4*)&Pl[wave][l16][kt * 16 + quad * 4] = w4;
    }
    // rescale accO (row q-index = quad*4+r; stats live at lanes 0..15)
    float ar[4];
#pragma unroll
    for (int r = 0; r < 4; r++) ar[r] = __shfl(alpha, quad * 4 + r);
#pragma unroll
    for (int dt = 0; dt < 8; dt++)
#pragma unroll
      for (int r = 0; r < 4; r++) accO[dt][r] *= ar[r];
    // PV: A=P[q][key], B=Vs[d][key]; 2 mfma per 16-d tile (keys 0-31, 32-63)
    bf16x8 pf0 = *(const bf16x8*)&Pl[wave][l16][quad * 8];
    bf16x8 pf1 = *(const bf16x8*)&Pl[wave][l16][32 + quad * 8];
#pragma unroll
    for (int dt = 0; dt < 8; dt++) {
      bf16x8 vf0 = *(const bf16x8*)&Vs[dt * 16 + l16][quad * 8];
      bf16x8 vf1 = *(const bf16x8*)&Vs[dt * 16 + l16][32 + quad * 8];
      accO[dt] = __builtin_amdgcn_mfma_f32_16x16x32_bf16(pf0, vf0, accO[dt], 0, 0, 0);
      accO[dt] = __builtin_amdgcn_mfma_f32_16x16x32_bf16(pf1, vf1, accO[dt], 0, 0, 0);
    }
  }
  // epilogue: O[q=quad*4+r][d=dt*16+l16] / l
  float linv[4];
#pragma unroll
  for (int r = 0; r < 4; r++) linv[r] = 1.f / __shfl(l_i, quad * 4 + r);
#pragma unroll
  for (int r = 0; r < 4; r++) {
    int qr = q0 + quad * 4 + r;
    if (qr < L) {
#pragma unroll
      for (int dt = 0; dt < 8; dt++)
        o[(size_t)qr * 1536 + h * 128 + dt * 16 + l16] = f2bf(accO[dt][r] * linv[r]);
    }
  }
}

// ---------------------------------------------------------------------------
extern "C" void kernel_launch(void* const* d_in, const int* in_sizes, int n_in,
                              void* d_out, int out_size, void* d_ws, size_t ws_size,
                              hipStream_t stream) {
  const float* x      = (const float*)d_in[0];
  const int* seq_lens = (const int*)d_in[1];
  const int* gsz      = (const int*)d_in[2];
  const float* freqs  = (const float*)d_in[3];
  const float* Wq     = (const float*)d_in[4];
  const float* bq     = (const float*)d_in[5];
  const float* Wk     = (const float*)d_in[6];
  const float* bk     = (const float*)d_in[7];
  const float* Wv     = (const float*)d_in[8];
  const float* bv     = (const float*)d_in[9];
  const float* Wo     = (const float*)d_in[10];
  const float* bo     = (const float*)d_in[11];
  const float* gq     = (const float*)d_in[12];
  const float* gk     = (const float*)d_in[13];
  float* out = (float*)d_out;   // fp32 output (proven round 5)

  const int DIM = 1536;
  const int L = in_sizes[0] / DIM;              // 5000
  const int Lpad = ((L + 63) / 64) * 64;        // 5056 (16B-aligned rows)
  const size_t SZW = (size_t)DIM * DIM;
  const size_t SZT = (size_t)L * DIM;

  // workspace (bf16): WT[4] | xb | qraw | kraw | vraw | vt | attn  (~111 MB)
  u16* wt   = (u16*)d_ws;
  u16* xb   = wt + 4 * SZW;
  u16* qraw = xb + SZT;
  u16* kraw = qraw + SZT;
  u16* vraw = kraw + SZT;
  u16* vtb  = vraw + SZT;
  u16* attn = vtb + (size_t)DIM * Lpad;

  const int mtiles = (L + 127) / 128;

  transpose4<<<dim3(48, 48, 4), dim3(32, 8), 0, stream>>>(Wq, Wk, Wv, Wo, wt);
  cast_f32_bf16<<<(int)((SZT / 4 + 255) / 256), 256, 0, stream>>>(x, xb, (int)(SZT / 4));
  gemm_bt<false><<<dim3(mtiles, 12), 256, 0, stream>>>(xb, wt,           bq, qraw, L);
  gemm_bt<false><<<dim3(mtiles, 12), 256, 0, stream>>>(xb, wt + SZW,     bk, kraw, L);
  gemm_bt<false><<<dim3(mtiles, 12), 256, 0, stream>>>(xb, wt + 2 * SZW, bv, vraw, L);
  rmsrope<<<dim3(L), 256, 0, stream>>>(qraw, kraw, gq, gk, freqs, gsz);
  transpose_v<<<dim3((L + 63) / 64, DIM / 64), 256, 0, stream>>>(vraw, vtb, L, Lpad);
  attn_mfma<<<dim3((L + 63) / 64, 12), 256, 0, stream>>>(qraw, kraw, vtb, attn, seq_lens, L, Lpad);
  gemm_bt<true><<<dim3(mtiles, 12), 256, 0, stream>>>(attn, wt + 3 * SZW, bo, out, L);
}

// Round 8
// 706.319 us; speedup vs baseline: 36.2912x; 1.1690x over previous
//
#include <hip/hip_runtime.h>

typedef unsigned short u16;
typedef unsigned int   u32;
typedef short bf16x8 __attribute__((ext_vector_type(8)));
typedef float f32x4  __attribute__((ext_vector_type(4)));

__device__ __forceinline__ float b2f(u16 u){ return __uint_as_float(((u32)u) << 16); }
__device__ __forceinline__ u16 f2bf(float f){
  u32 u = __float_as_uint(f);
  return (u16)((u + 0x7fffu + ((u >> 16) & 1u)) >> 16);  // RNE
}

// ---------------------------------------------------------------------------
// Transpose+cast four fp32 1536x1536 weights into bf16 WT[n][k]=W[k][n].
// ---------------------------------------------------------------------------
__global__ __launch_bounds__(256) void transpose4(
    const float* __restrict__ Wq, const float* __restrict__ Wk,
    const float* __restrict__ Wv, const float* __restrict__ Wo, u16* __restrict__ wt)
{
  __shared__ float tile[32][33];
  const float* src = blockIdx.z == 0 ? Wq : blockIdx.z == 1 ? Wk : blockIdx.z == 2 ? Wv : Wo;
  u16* dst = wt + (size_t)blockIdx.z * 1536 * 1536;
  const int bx = blockIdx.x * 32, by = blockIdx.y * 32;
  const int tx = threadIdx.x, ty = threadIdx.y;  // 32 x 8
#pragma unroll
  for (int i = 0; i < 32; i += 8)
    tile[ty + i][tx] = src[(size_t)(by + ty + i) * 1536 + bx + tx];
  __syncthreads();
#pragma unroll
  for (int i = 0; i < 32; i += 8)
    dst[(size_t)(bx + ty + i) * 1536 + by + tx] = f2bf(tile[tx][ty + i]);
}

// fp32 -> bf16 cast for x.
__global__ __launch_bounds__(256) void cast_f32_bf16(
    const float* __restrict__ src, u16* __restrict__ dst, int n4)
{
  int i = blockIdx.x * 256 + threadIdx.x;
  if (i < n4) {
    float4 f = ((const float4*)src)[i];
    ushort4 o;
    o.x = f2bf(f.x); o.y = f2bf(f.y); o.z = f2bf(f.z); o.w = f2bf(f.w);
    ((ushort4*)dst)[i] = o;
  }
}

// ---------------------------------------------------------------------------
// bf16 transpose: src[L][1536] -> dst[1536][Lpad], zero-padded keys >= L.
// ---------------------------------------------------------------------------
__global__ __launch_bounds__(256) void transpose_v(
    const u16* __restrict__ src, u16* __restrict__ dst, int L, int Lpad)
{
  __shared__ u16 tile[64][72];
  const int kb = blockIdx.x * 64, c0 = blockIdx.y * 64;
  const int tid = threadIdx.x;
#pragma unroll
  for (int i = 0; i < 2; i++) {
    int slot = tid + i * 256;
    int row = slot >> 3, oct = slot & 7;
    bf16x8 z = {0, 0, 0, 0, 0, 0, 0, 0};
    int key = kb + row;
    if (key < L) z = *(const bf16x8*)(src + (size_t)key * 1536 + c0 + oct * 8);
    *(bf16x8*)&tile[row][oct * 8] = z;
  }
  __syncthreads();
#pragma unroll
  for (int i = 0; i < 2; i++) {
    int slot = tid + i * 256;
    int d = slot >> 3, oct = slot & 7;
    bf16x8 z;
#pragma unroll
    for (int j = 0; j < 8; j++) z[j] = (short)tile[oct * 8 + j][d];
    *(bf16x8*)(dst + (size_t)(c0 + d) * Lpad + kb + oct * 8) = z;
  }
}

// ---------------------------------------------------------------------------
// GEMM core: C[M][1536] = A @ BT^T + bias. bf16 MFMA, fp32 acc.
// 128x128 tile, 4 waves 2x2, 4x4 mfma 16x16x32.  [verified r6/r7]
// ---------------------------------------------------------------------------
template<bool F32OUT>
__device__ __forceinline__ void gemm_core(
    const u16* __restrict__ A, const u16* __restrict__ BT,
    const float* __restrict__ bias, void* __restrict__ Cv, int M,
    int m0, int n0)
{
  __shared__ u16 As[128][40];
  __shared__ u16 Bs[128][40];
  const int tid = threadIdx.x;
  const int wave = tid >> 6, lane = tid & 63;
  const int wm = (wave & 1) * 64, wn = (wave >> 1) * 64;
  const int l16 = lane & 15, quad = lane >> 4;
  f32x4 acc[4][4] = {};
  for (int k0 = 0; k0 < 1536; k0 += 32) {
    __syncthreads();
#pragma unroll
    for (int i = 0; i < 2; i++) {
      int c = tid + i * 256;
      int row = c >> 2, col = (c & 3) * 8;
      bf16x8 av = {0, 0, 0, 0, 0, 0, 0, 0};
      int gr = m0 + row;
      if (gr < M) av = *(const bf16x8*)(A + (size_t)gr * 1536 + k0 + col);
      *(bf16x8*)&As[row][col] = av;
      *(bf16x8*)&Bs[row][col] = *(const bf16x8*)(BT + (size_t)(n0 + row) * 1536 + k0 + col);
    }
    __syncthreads();
    bf16x8 af[4], bfr[4];
#pragma unroll
    for (int mt = 0; mt < 4; mt++) af[mt] = *(const bf16x8*)&As[wm + mt * 16 + l16][quad * 8];
#pragma unroll
    for (int nt = 0; nt < 4; nt++) bfr[nt] = *(const bf16x8*)&Bs[wn + nt * 16 + l16][quad * 8];
#pragma unroll
    for (int mt = 0; mt < 4; mt++)
#pragma unroll
      for (int nt = 0; nt < 4; nt++)
        acc[mt][nt] = __builtin_amdgcn_mfma_f32_16x16x32_bf16(af[mt], bfr[nt], acc[mt][nt], 0, 0, 0);
  }
#pragma unroll
  for (int nt = 0; nt < 4; nt++) {
    int col = n0 + wn + nt * 16 + l16;
    float bv = bias[col];
#pragma unroll
    for (int mt = 0; mt < 4; mt++) {
      int rowb = m0 + wm + mt * 16 + quad * 4;
#pragma unroll
      for (int r = 0; r < 4; r++) {
        int row = rowb + r;
        if (row < M) {
          float val = acc[mt][nt][r] + bv;
          if (F32OUT) ((float*)Cv)[(size_t)row * 1536 + col] = val;
          else        ((u16*)Cv)[(size_t)row * 1536 + col] = f2bf(val);
        }
      }
    }
  }
}

// Fused Q/K/V projection: blockIdx.z selects weight/bias/output.
__global__ __launch_bounds__(256) void gemm_qkv(
    const u16* __restrict__ A, const u16* __restrict__ wt,
    const float* __restrict__ bq, const float* __restrict__ bk, const float* __restrict__ bv,
    u16* __restrict__ outbase, int M, size_t SZW, size_t SZT)
{
  const int z = blockIdx.z;
  const u16* BT = wt + (size_t)z * SZW;
  const float* bias = z == 0 ? bq : z == 1 ? bk : bv;
  u16* C = outbase + (size_t)z * SZT;
  gemm_core<false>(A, BT, bias, C, M, blockIdx.x * 128, blockIdx.y * 128);
}

__global__ __launch_bounds__(256) void gemm_out(
    const u16* __restrict__ A, const u16* __restrict__ BT,
    const float* __restrict__ bias, float* __restrict__ C, int M)
{
  gemm_core<true>(A, BT, bias, C, M, blockIdx.x * 128, blockIdx.y * 128);
}

// ---------------------------------------------------------------------------
// In-place RMSNorm (dim 1536) + per-head RoPE on bf16 q/k; fp32 gains/freqs.
// ---------------------------------------------------------------------------
__global__ __launch_bounds__(256) void rmsrope(
    u16* __restrict__ qb, u16* __restrict__ kb,
    const float* __restrict__ gq, const float* __restrict__ gk,
    const float* __restrict__ freqs, const int* __restrict__ gsz)
{
  const int s = blockIdx.x, tid = threadIdx.x;
  const size_t base = (size_t)s * 1536;
  float qv[6], kv[6];
  float sq = 0.f, sk = 0.f;
#pragma unroll
  for (int i = 0; i < 6; i++) {
    float a = b2f(qb[base + tid * 6 + i]); qv[i] = a; sq += a * a;
    float b = b2f(kb[base + tid * 6 + i]); kv[i] = b; sk += b * b;
  }
#pragma unroll
  for (int d2 = 1; d2 < 64; d2 <<= 1) { sq += __shfl_xor(sq, d2); sk += __shfl_xor(sk, d2); }
  __shared__ float red[8];
  const int wave = tid >> 6, lane = tid & 63;
  if (lane == 0) { red[wave] = sq; red[4 + wave] = sk; }
  __syncthreads();
  sq = red[0] + red[1] + red[2] + red[3];
  sk = red[4] + red[5] + red[6] + red[7];
  const float rq = rsqrtf(sq * (1.f / 1536.f) + 1e-6f);
  const float rk = rsqrtf(sk * (1.f / 1536.f) + 1e-6f);
  const int F = gsz[0], H = gsz[1], W = gsz[2];
  const int sl = F * H * W;
  const bool rope = s < sl;
  int pf = 0, ph = 0, pw = 0;
  if (rope) { pf = s / (H * W); int rr = s - pf * (H * W); ph = rr / W; pw = rr - ph * W; }
#pragma unroll
  for (int pp = 0; pp < 3; pp++) {
    const int j0 = tid * 6 + pp * 2;
    float qre = qv[pp * 2]     * rq * gq[j0];
    float qim = qv[pp * 2 + 1] * rq * gq[j0 + 1];
    float kre = kv[pp * 2]     * rk * gk[j0];
    float kim = kv[pp * 2 + 1] * rk * gk[j0 + 1];
    if (rope) {
      const int ti = (j0 & 127) >> 1;
      const int pos = ti < 22 ? pf : (ti < 43 ? ph : pw);
      const float ang = freqs[pos * 64 + ti];
      const float cs = cosf(ang), sn = sinf(ang);
      float t1 = qre * cs - qim * sn; qim = qre * sn + qim * cs; qre = t1;
      float t2 = kre * cs - kim * sn; kim = kre * sn + kim * cs; kre = t2;
    }
    qb[base + j0] = f2bf(qre); qb[base + j0 + 1] = f2bf(qim);
    kb[base + j0] = f2bf(kre); kb[base + j0 + 1] = f2bf(kim);
  }
}

// ---------------------------------------------------------------------------
// MFMA flash attention, 64-key tiles, register-double-buffered K/V staging.
// Block = 4 waves = 64 q rows (16/wave), one head. Q pre-scaled by
// (1/sqrt(d))*log2(e); softmax in log2 domain; P truncation-packed.
// ---------------------------------------------------------------------------
__global__ __launch_bounds__(256) void attn_mfma(
    const u16* __restrict__ q, const u16* __restrict__ k, const u16* __restrict__ vt,
    u16* __restrict__ o, const int* __restrict__ seq_lens, int L, int Lpad)
{
  __shared__ u16 Ks[64][136];    // K rows [key][d], pad 8
  __shared__ u16 Vs[128][72];    // V^T [d][key], pad 8
  __shared__ u16 Pl[4][16][72];  // per-wave P [q][key], pad 8
  const int tid = threadIdx.x, wave = tid >> 6, lane = tid & 63;
  const int l16 = lane & 15, quad = lane >> 4;
  const int h = blockIdx.y;
  const int seqlen = seq_lens[0];
  const int q0 = blockIdx.x * 64 + wave * 16;
  const float SC = 0.12752551286084934f;   // (1/sqrt(128)) * log2(e)

  // staging coordinates (per thread, fixed)
  int krow[4], kcol[4], vd[4], voct[4];
#pragma unroll
  for (int i = 0; i < 4; i++) {
    int slot = tid + i * 256;
    krow[i] = slot >> 4; kcol[i] = (slot & 15) * 8;
    vd[i]   = slot >> 3; voct[i] = (slot & 7) * 8;
  }
  const u16* kp  = k + h * 128;
  const u16* vtp = vt + (size_t)h * 128 * Lpad;

  // Q fragments, pre-scaled to log2-domain (loop-invariant)
  bf16x8 Qf[4];
  {
    int qr = q0 + l16;
#pragma unroll
    for (int ds = 0; ds < 4; ds++) {
      bf16x8 z = {0, 0, 0, 0, 0, 0, 0, 0};
      if (qr < L) {
        bf16x8 raw = *(const bf16x8*)(q + (size_t)qr * 1536 + h * 128 + ds * 32 + quad * 8);
#pragma unroll
        for (int j = 0; j < 8; j++) z[j] = (short)f2bf(b2f((u16)raw[j]) * SC);
      }
      Qf[ds] = z;
    }
  }
  f32x4 accO[8];
#pragma unroll
  for (int dt = 0; dt < 8; dt++) accO[dt] = (f32x4){0.f, 0.f, 0.f, 0.f};
  float m_i = -1e30f, l_i = 0.f;

  const int ntile = (seqlen + 63) >> 6;
  bf16x8 kpre[4], vpre[4];
  // prefetch tile 0
#pragma unroll
  for (int i = 0; i < 4; i++) {
    int row = krow[i];
    bf16x8 z = {0, 0, 0, 0, 0, 0, 0, 0};
    if (row < seqlen) z = *(const bf16x8*)(kp + (size_t)row * 1536 + kcol[i]);
    kpre[i] = z;
    vpre[i] = *(const bf16x8*)(vtp + (size_t)vd[i] * Lpad + voct[i]);
  }

  for (int t = 0; t < ntile; t++) {
    const int kb = t * 64;
    __syncthreads();   // all waves done reading Ks/Vs of tile t-1
#pragma unroll
    for (int i = 0; i < 4; i++) {
      *(bf16x8*)&Ks[krow[i]][kcol[i]] = kpre[i];
      *(bf16x8*)&Vs[vd[i]][voct[i]]   = vpre[i];
    }
    __syncthreads();   // staging visible
    if (t + 1 < ntile) {
      const int kb2 = kb + 64;
#pragma unroll
      for (int i = 0; i < 4; i++) {
        int row = kb2 + krow[i];
        bf16x8 z = {0, 0, 0, 0, 0, 0, 0, 0};
        if (row < seqlen) z = *(const bf16x8*)(kp + (size_t)row * 1536 + kcol[i]);
        kpre[i] = z;
        vpre[i] = *(const bf16x8*)(vtp + (size_t)vd[i] * Lpad + kb2 + voct[i]);
      }
    }

    // S^T: four 16(key)x16(q) tiles over d=128 (log2-domain scores)
    const bool full = (kb + 64 <= seqlen);
    float sv[16];
    float tmax = -1e30f;
#pragma unroll
    for (int kt = 0; kt < 4; kt++) {
      f32x4 a = {0.f, 0.f, 0.f, 0.f};
#pragma unroll
      for (int ds = 0; ds < 4; ds++) {
        bf16x8 kf = *(const bf16x8*)&Ks[kt * 16 + l16][ds * 32 + quad * 8];
        a = __builtin_amdgcn_mfma_f32_16x16x32_bf16(kf, Qf[ds], a, 0, 0, 0);
      }
      if (full) {
#pragma unroll
        for (int r = 0; r < 4; r++) { sv[kt * 4 + r] = a[r]; tmax = fmaxf(tmax, a[r]); }
      } else {
#pragma unroll
        for (int r = 0; r < 4; r++) {
          int key = kb + kt * 16 + quad * 4 + r;
          float s = (key < seqlen) ? a[r] : -1e30f;
          sv[kt * 4 + r] = s;
          tmax = fmaxf(tmax, s);
        }
      }
    }
    tmax = fmaxf(tmax, __shfl_xor(tmax, 16));
    tmax = fmaxf(tmax, __shfl_xor(tmax, 32));
    const float mnew = fmaxf(m_i, tmax);
    const float alpha = exp2f(m_i - mnew);
    float psum = 0.f;
    u16 pk[16];
#pragma unroll
    for (int i2 = 0; i2 < 16; i2++) {
      float p = exp2f(sv[i2] - mnew);
      u32 pu = __float_as_uint(p) & 0xffff0000u;   // truncate to bf16
      psum += __uint_as_float(pu);                 // sum what PV will use
      pk[i2] = (u16)(pu >> 16);
    }
    psum += __shfl_xor(psum, 16);
    psum += __shfl_xor(psum, 32);
    l_i = l_i * alpha + psum;
    m_i = mnew;
#pragma unroll
    for (int kt = 0; kt < 4; kt++) {
      ushort4 w4 = { pk[kt * 4], pk[kt * 4 + 1], pk[kt * 4 + 2], pk[kt * 4 + 3] };
      *(ushort4*)&Pl[wave][l16][kt * 16 + quad * 4] = w4;
    }
    float ar[4];
#pragma unroll
    for (int r = 0; r < 4; r++) ar[r] = __shfl(alpha, quad * 4 + r);
#pragma unroll
    for (int dt = 0; dt < 8; dt++)
#pragma unroll
      for (int r = 0; r < 4; r++) accO[dt][r] *= ar[r];
    bf16x8 pf0 = *(const bf16x8*)&Pl[wave][l16][quad * 8];
    bf16x8 pf1 = *(const bf16x8*)&Pl[wave][l16][32 + quad * 8];
#pragma unroll
    for (int dt = 0; dt < 8; dt++) {
      bf16x8 vf0 = *(const bf16x8*)&Vs[dt * 16 + l16][quad * 8];
      bf16x8 vf1 = *(const bf16x8*)&Vs[dt * 16 + l16][32 + quad * 8];
      accO[dt] = __builtin_amdgcn_mfma_f32_16x16x32_bf16(pf0, vf0, accO[dt], 0, 0, 0);
      accO[dt] = __builtin_amdgcn_mfma_f32_16x16x32_bf16(pf1, vf1, accO[dt], 0, 0, 0);
    }
  }
  // epilogue: O[q=quad*4+r][d=dt*16+l16] / l
  float linv[4];
#pragma unroll
  for (int r = 0; r < 4; r++) linv[r] = 1.f / __shfl(l_i, quad * 4 + r);
#pragma unroll
  for (int r = 0; r < 4; r++) {
    int qr = q0 + quad * 4 + r;
    if (qr < L) {
#pragma unroll
      for (int dt = 0; dt < 8; dt++)
        o[(size_t)qr * 1536 + h * 128 + dt * 16 + l16] = f2bf(accO[dt][r] * linv[r]);
    }
  }
}

// ---------------------------------------------------------------------------
extern "C" void kernel_launch(void* const* d_in, const int* in_sizes, int n_in,
                              void* d_out, int out_size, void* d_ws, size_t ws_size,
                              hipStream_t stream) {
  const float* x      = (const float*)d_in[0];
  const int* seq_lens = (const int*)d_in[1];
  const int* gsz      = (const int*)d_in[2];
  const float* freqs  = (const float*)d_in[3];
  const float* Wq     = (const float*)d_in[4];
  const float* bq     = (const float*)d_in[5];
  const float* Wk     = (const float*)d_in[6];
  const float* bk     = (const float*)d_in[7];
  const float* Wv     = (const float*)d_in[8];
  const float* bv     = (const float*)d_in[9];
  const float* Wo     = (const float*)d_in[10];
  const float* bo     = (const float*)d_in[11];
  const float* gq     = (const float*)d_in[12];
  const float* gk     = (const float*)d_in[13];
  float* out = (float*)d_out;   // fp32 output (proven round 5)

  const int DIM = 1536;
  const int L = in_sizes[0] / DIM;              // 5000
  const int Lpad = ((L + 63) / 64) * 64;        // 5056
  const size_t SZW = (size_t)DIM * DIM;
  const size_t SZT = (size_t)L * DIM;

  // workspace (bf16): WT[4] | xb | qraw | kraw | vraw | vt | attn
  u16* wt   = (u16*)d_ws;
  u16* xb   = wt + 4 * SZW;
  u16* qraw = xb + SZT;
  u16* kraw = qraw + SZT;
  u16* vraw = kraw + SZT;
  u16* vtb  = vraw + SZT;
  u16* attn = vtb + (size_t)DIM * Lpad;

  const int mtiles = (L + 127) / 128;

  transpose4<<<dim3(48, 48, 4), dim3(32, 8), 0, stream>>>(Wq, Wk, Wv, Wo, wt);
  cast_f32_bf16<<<(int)((SZT / 4 + 255) / 256), 256, 0, stream>>>(x, xb, (int)(SZT / 4));
  gemm_qkv<<<dim3(mtiles, 12, 3), 256, 0, stream>>>(xb, wt, bq, bk, bv, qraw, L, SZW, SZT);
  rmsrope<<<dim3(L), 256, 0, stream>>>(qraw, kraw, gq, gk, freqs, gsz);
  transpose_v<<<dim3((L + 63) / 64, DIM / 64), 256, 0, stream>>>(vraw, vtb, L, Lpad);
  attn_mfma<<<dim3((L + 63) / 64, 12), 256, 0, stream>>>(qraw, kraw, vtb, attn, seq_lens, L, Lpad);
  gemm_out<<<dim3(mtiles, 12), 256, 0, stream>>>(attn, wt + 3 * SZW, bo, out, L);
}